// Round 1
// baseline (140.497 us; speedup 1.0000x reference)
//
#include <hip/hip_runtime.h>
#include <math.h>

#define BB   32
#define CIN  16
#define HH   64
#define SS   128
#define STILE 8

// ---------------------------------------------------------------------------
// Kernel 1: fused conv stack -> h -> Q,P   (one block per (batch, 8-pos tile))
//   t1 = conv11(x) (1x1), t2 = conv21(x) (1x1)         [computed in LDS]
//   x1 = conv12(t1) k=3 d=3, x2 = conv22(t2) k=5 d=5, x3 = conv31(x) k=5 d=1
//   h  = relu([x1;x2;x3] @ Wf.T + bf)
//   Q  = h @ W1[:, :64].T          (sender term, indexed by j)
//   P  = h @ W1[:, 64:].T + b1     (receiver term, indexed by i)
// All accumulation in fp64: float*float products are exact in double, so we
// track the "true" value to ~1e-15 -> argmax decisions robust vs np reference.
// ---------------------------------------------------------------------------
__global__ __launch_bounds__(256) void fused_front(
    const float* __restrict__ x,
    const float* __restrict__ w11, const float* __restrict__ b11,
    const float* __restrict__ w12, const float* __restrict__ b12,
    const float* __restrict__ w21, const float* __restrict__ b21,
    const float* __restrict__ w22, const float* __restrict__ b22,
    const float* __restrict__ w31, const float* __restrict__ b31,
    const float* __restrict__ wf,  const float* __restrict__ bf,
    const float* __restrict__ w1,  const float* __restrict__ b1,
    double* __restrict__ Qg, double* __restrict__ Pg)
{
    const int b  = blockIdx.y;
    const int s0 = blockIdx.x * STILE;
    const int t  = threadIdx.x;

    // LDS tiles (doubles). Column windows relative to s0:
    //   xl  : s0-10 .. s0+17  (28 cols)  -- raw input, zero outside [0,S)
    //   t1l : s0-3  .. s0+10  (14 cols)  -- zero (NOT bias) outside [0,S)
    //   t2l : s0-10 .. s0+17  (28 cols)
    __shared__ double xl [CIN][28];
    __shared__ double t1l[HH][14];
    __shared__ double t2l[HH][28];
    __shared__ double x123[STILE][192];
    __shared__ double hl [STILE][HH];

    // phase 0: load input slice (zero-padded)
    for (int idx = t; idx < CIN * 28; idx += 256) {
        int c = idx / 28, col = idx % 28;
        int g = s0 - 10 + col;
        xl[c][col] = (g >= 0 && g < SS) ? (double)x[(b * CIN + c) * SS + g] : 0.0;
    }
    __syncthreads();

    // phase 0b: pointwise convs t1, t2. SAME-padding of the *next* conv means
    // out-of-range columns must be exactly 0 (bias NOT applied there).
    for (int idx = t; idx < HH * 14 + HH * 28; idx += 256) {
        if (idx < HH * 14) {
            int k = idx & 63, col = idx >> 6;           // col in [0,14)
            int g = s0 - 3 + col;
            double acc = 0.0;
            if (g >= 0 && g < SS) {
                acc = (double)b11[k];
                for (int c = 0; c < CIN; ++c)
                    acc += xl[c][col + 7] * (double)w11[k * CIN + c];
            }
            t1l[k][col] = acc;
        } else {
            int idx2 = idx - HH * 14;
            int k = idx2 & 63, col = idx2 >> 6;         // col in [0,28)
            int g = s0 - 10 + col;
            double acc = 0.0;
            if (g >= 0 && g < SS) {
                acc = (double)b21[k];
                for (int c = 0; c < CIN; ++c)
                    acc += xl[c][col] * (double)w21[k * CIN + c];
            }
            t2l[k][col] = acc;
        }
    }
    __syncthreads();

    // lane owns output channel n; wave w owns positions p = 2w, 2w+1.
    // LDS reads below are wave-uniform (broadcast, conflict-free); weight
    // reads stream per-lane rows (L1/L2 resident across blocks).
    const int n = t & 63;
    const int w = t >> 6;
    const float* r12 = w12 + n * 192;   // (n, mm, tap3)
    const float* r22 = w22 + n * 320;   // (n, mm, tap5)
    const float* r31 = w31 + n * 80;    // (n, c,  tap5)

    // phase 1: dilated/regular convs -> x123 = [x1 | x2 | x3]
    for (int q = 0; q < 2; ++q) {
        const int p = 2 * w + q;
        double a1 = (double)b12[n];
        for (int mm = 0; mm < HH; ++mm) {
            a1 += t1l[mm][p]     * (double)r12[mm * 3 + 0]
                + t1l[mm][p + 3] * (double)r12[mm * 3 + 1]
                + t1l[mm][p + 6] * (double)r12[mm * 3 + 2];
        }
        double a2 = (double)b22[n];
        for (int mm = 0; mm < HH; ++mm) {
            a2 += t2l[mm][p]      * (double)r22[mm * 5 + 0]
                + t2l[mm][p + 5]  * (double)r22[mm * 5 + 1]
                + t2l[mm][p + 10] * (double)r22[mm * 5 + 2]
                + t2l[mm][p + 15] * (double)r22[mm * 5 + 3]
                + t2l[mm][p + 20] * (double)r22[mm * 5 + 4];
        }
        double a3 = (double)b31[n];
        for (int c = 0; c < CIN; ++c) {
            #pragma unroll
            for (int tp = 0; tp < 5; ++tp)
                a3 += xl[c][p + 8 + tp] * (double)r31[c * 5 + tp];
        }
        x123[p][n] = a1; x123[p][64 + n] = a2; x123[p][128 + n] = a3;
    }
    __syncthreads();

    // phase 2a: fc_final + relu -> h
    {
        const float* rf = wf + n * 192;
        for (int q = 0; q < 2; ++q) {
            const int p = 2 * w + q;
            double acc = (double)bf[n];
            for (int m = 0; m < 192; ++m)
                acc += x123[p][m] * (double)rf[m];
            hl[p][n] = acc > 0.0 ? acc : 0.0;
        }
    }
    __syncthreads();

    // phase 2b: Q (sender half of fc1_w), P (receiver half + bias)
    {
        const float* r1 = w1 + n * 128;
        for (int q = 0; q < 2; ++q) {
            const int p = 2 * w + q;
            double qv = 0.0, pv = (double)b1[n];
            for (int m = 0; m < HH; ++m) {
                qv += hl[p][m] * (double)r1[m];
                pv += hl[p][m] * (double)r1[64 + m];
            }
            long base = ((long)b * SS + (s0 + p)) * HH + n;
            Qg[base] = qv;
            Pg[base] = pv;
        }
    }
}

// ---------------------------------------------------------------------------
// Kernel 2: edge sign test. 16x16 edge tiles; out[b,i,j] = (j>i) && sign>=0.
//   acc = (b2[0]-b2[1]) + g0 - g1 + sum_k relu(P[i,k]+Q[j,k]) * (w2[0,k]-w2[1,k])
// argmax(softmax(z)) with first-index tie-break  ==  (z0 >= z1) -> class 0.
// ---------------------------------------------------------------------------
__global__ __launch_bounds__(256) void edges(
    const double* __restrict__ Qg, const double* __restrict__ Pg,
    const float* __restrict__ w2, const float* __restrict__ b2,
    const float* __restrict__ gum, float* __restrict__ out)
{
    const int b   = blockIdx.y;
    const int tit = blockIdx.x >> 3;    // i-tile
    const int tjt = blockIdx.x & 7;     // j-tile
    const int t   = threadIdx.x;
    const int ti  = t >> 4, tj = t & 15;
    const int i   = tit * 16 + ti;
    const int j   = tjt * 16 + tj;
    float* op = out + ((long)b * SS + i) * SS + j;

    if (tjt < tit) { *op = 0.0f; return; }   // whole tile strictly below diag

    // stride 66 doubles: banks (4*tj + 2k) & 31 -> worst 2-way (free)
    __shared__ double Pl[16][66];
    __shared__ double Ql[16][66];
    __shared__ double dwl[64];

    if (t < 64) dwl[t] = (double)w2[t] - (double)w2[64 + t];
    for (int idx = t; idx < 1024; idx += 256) {
        int r = idx >> 6, c = idx & 63;
        Pl[r][c] = Pg[((long)b * SS + tit * 16 + r) * HH + c];
        Ql[r][c] = Qg[((long)b * SS + tjt * 16 + r) * HH + c];
    }
    __syncthreads();

    if (j <= i) { *op = 0.0f; return; }

    long e = (long)b * SS * SS + (long)i * SS + j;
    double u0 = (double)gum[e * 2 + 0];
    double u1 = (double)gum[e * 2 + 1];
    double acc = ((double)b2[0] - (double)b2[1]) - log(-log(u0)) + log(-log(u1));
    #pragma unroll
    for (int k = 0; k < 64; ++k) {
        double v = Pl[ti][k] + Ql[tj][k];
        v = v > 0.0 ? v : 0.0;
        acc += v * dwl[k];
    }
    *op = (acc >= 0.0) ? 1.0f : 0.0f;
}

extern "C" void kernel_launch(void* const* d_in, const int* in_sizes, int n_in,
                              void* d_out, int out_size, void* d_ws, size_t ws_size,
                              hipStream_t stream) {
    const float* data = (const float*)d_in[0];
    const float* w11  = (const float*)d_in[1];
    const float* b11  = (const float*)d_in[2];
    const float* w12  = (const float*)d_in[3];
    const float* b12  = (const float*)d_in[4];
    const float* w21  = (const float*)d_in[5];
    const float* b21  = (const float*)d_in[6];
    const float* w22  = (const float*)d_in[7];
    const float* b22  = (const float*)d_in[8];
    const float* w31  = (const float*)d_in[9];
    const float* b31  = (const float*)d_in[10];
    const float* wf   = (const float*)d_in[11];
    const float* bf   = (const float*)d_in[12];
    const float* w1   = (const float*)d_in[13];
    const float* b1   = (const float*)d_in[14];
    const float* w2   = (const float*)d_in[15];
    const float* b2   = (const float*)d_in[16];
    const float* gum  = (const float*)d_in[17];
    float* out = (float*)d_out;

    double* Qg = (double*)d_ws;                      // B*S*H doubles = 2 MB
    double* Pg = Qg + (long)BB * SS * HH;            // + 2 MB

    fused_front<<<dim3(SS / STILE, BB), 256, 0, stream>>>(
        data, w11, b11, w12, b12, w21, b21, w22, b22, w31, b31,
        wf, bf, w1, b1, Qg, Pg);
    edges<<<dim3(64, BB), 256, 0, stream>>>(Qg, Pg, w2, b2, gum, out);
}

// Round 2
// 126.829 us; speedup vs baseline: 1.1078x; 1.1078x over previous
//
#include <hip/hip_runtime.h>
#include <math.h>

#define BB   32
#define CIN  16
#define HH   64
#define SS   128
#define STILE 8

// ---------------------------------------------------------------------------
// Kernel 1: fused conv stack -> h -> Q,P.  One block per (batch, 8-pos tile),
// 512 threads = 8 waves; wave w owns position p=w, lane owns channel n.
// fp64 accumulation throughout, but split into independent partial sums
// (4-10 chains) so the f64 FMA latency is hidden by ILP.
// ---------------------------------------------------------------------------
__global__ __launch_bounds__(512, 4) void fused_front(
    const float* __restrict__ x,
    const float* __restrict__ w11, const float* __restrict__ b11,
    const float* __restrict__ w12, const float* __restrict__ b12,
    const float* __restrict__ w21, const float* __restrict__ b21,
    const float* __restrict__ w22, const float* __restrict__ b22,
    const float* __restrict__ w31, const float* __restrict__ b31,
    const float* __restrict__ wf,  const float* __restrict__ bf,
    const float* __restrict__ w1,  const float* __restrict__ b1,
    double* __restrict__ Qg, double* __restrict__ Pg)
{
    const int b  = blockIdx.y;
    const int s0 = blockIdx.x * STILE;
    const int t  = threadIdx.x;

    // Column windows relative to s0:
    //   xl  : s0-10 .. s0+17  (28 cols)  zero outside [0,S)
    //   t1l : s0-3  .. s0+10  (14 cols)  zero (NOT bias) outside [0,S)
    //   t2l : s0-10 .. s0+17  (28 cols)
    __shared__ double xl [CIN][28];
    __shared__ double t1l[HH][14];
    __shared__ double t2l[HH][28];
    __shared__ double x123[STILE][192];
    __shared__ double hl [STILE][HH];

    // phase 0: load input slice (zero-padded). 448 items, one shot.
    if (t < CIN * 28) {
        int c = t / 28, col = t % 28;
        int g = s0 - 10 + col;
        xl[c][col] = (g >= 0 && g < SS) ? (double)x[(b * CIN + c) * SS + g] : 0.0;
    }
    __syncthreads();

    // phase 0b: pointwise convs t1, t2 (2688 items / 512 threads).
    for (int idx = t; idx < HH * 14 + HH * 28; idx += 512) {
        if (idx < HH * 14) {
            int k = idx & 63, col = idx >> 6;           // col in [0,14)
            int g = s0 - 3 + col;
            double acc = 0.0;
            if (g >= 0 && g < SS) {
                double u0 = (double)b11[k], u1 = 0.0;
                #pragma unroll
                for (int c = 0; c < CIN; c += 2) {
                    u0 += xl[c][col + 7]     * (double)w11[k * CIN + c];
                    u1 += xl[c + 1][col + 7] * (double)w11[k * CIN + c + 1];
                }
                acc = u0 + u1;
            }
            t1l[k][col] = acc;
        } else {
            int idx2 = idx - HH * 14;
            int k = idx2 & 63, col = idx2 >> 6;         // col in [0,28)
            int g = s0 - 10 + col;
            double acc = 0.0;
            if (g >= 0 && g < SS) {
                double u0 = (double)b21[k], u1 = 0.0;
                #pragma unroll
                for (int c = 0; c < CIN; c += 2) {
                    u0 += xl[c][col]     * (double)w21[k * CIN + c];
                    u1 += xl[c + 1][col] * (double)w21[k * CIN + c + 1];
                }
                acc = u0 + u1;
            }
            t2l[k][col] = acc;
        }
    }
    __syncthreads();

    const int n = t & 63;        // output channel (lane)
    const int p = t >> 6;        // position (wave) 0..7

    const float* r12 = w12 + n * 192;   // (n, mm, tap3)
    const float* r22 = w22 + n * 320;   // (n, mm, tap5)
    const float* r31 = w31 + n * 80;    // (n, c,  tap5)

    // phase 1: dilated/regular convs -> x123 = [x1 | x2 | x3]
    {
        // x1: 6 independent chains of 32
        double s0a=0, s1a=0, s2a=0, s0b=0, s1b=0, s2b=0;
        #pragma unroll 8
        for (int mm = 0; mm < HH; mm += 2) {
            s0a += t1l[mm][p]         * (double)r12[mm * 3 + 0];
            s1a += t1l[mm][p + 3]     * (double)r12[mm * 3 + 1];
            s2a += t1l[mm][p + 6]     * (double)r12[mm * 3 + 2];
            s0b += t1l[mm + 1][p]     * (double)r12[mm * 3 + 3];
            s1b += t1l[mm + 1][p + 3] * (double)r12[mm * 3 + 4];
            s2b += t1l[mm + 1][p + 6] * (double)r12[mm * 3 + 5];
        }
        x123[p][n] = (double)b12[n] + ((s0a + s0b) + (s1a + s1b)) + (s2a + s2b);

        // x2: 10 independent chains of 32
        double c0=0,c1=0,c2=0,c3=0,c4=0, d0=0,d1=0,d2=0,d3=0,d4=0;
        #pragma unroll 4
        for (int mm = 0; mm < HH; mm += 2) {
            c0 += t2l[mm][p]          * (double)r22[mm * 5 + 0];
            c1 += t2l[mm][p + 5]      * (double)r22[mm * 5 + 1];
            c2 += t2l[mm][p + 10]     * (double)r22[mm * 5 + 2];
            c3 += t2l[mm][p + 15]     * (double)r22[mm * 5 + 3];
            c4 += t2l[mm][p + 20]     * (double)r22[mm * 5 + 4];
            d0 += t2l[mm + 1][p]      * (double)r22[mm * 5 + 5];
            d1 += t2l[mm + 1][p + 5]  * (double)r22[mm * 5 + 6];
            d2 += t2l[mm + 1][p + 10] * (double)r22[mm * 5 + 7];
            d3 += t2l[mm + 1][p + 15] * (double)r22[mm * 5 + 8];
            d4 += t2l[mm + 1][p + 20] * (double)r22[mm * 5 + 9];
        }
        x123[p][64 + n] = (double)b22[n]
            + (((c0 + d0) + (c1 + d1)) + ((c2 + d2) + (c3 + d3))) + (c4 + d4);

        // x3: 5 independent chains of 16
        double e0=0,e1=0,e2=0,e3=0,e4=0;
        #pragma unroll
        for (int c = 0; c < CIN; ++c) {
            e0 += xl[c][p + 8]  * (double)r31[c * 5 + 0];
            e1 += xl[c][p + 9]  * (double)r31[c * 5 + 1];
            e2 += xl[c][p + 10] * (double)r31[c * 5 + 2];
            e3 += xl[c][p + 11] * (double)r31[c * 5 + 3];
            e4 += xl[c][p + 12] * (double)r31[c * 5 + 4];
        }
        x123[p][128 + n] = (double)b31[n] + ((e0 + e1) + (e2 + e3)) + e4;
    }
    __syncthreads();

    // phase 2a: fc_final + relu -> h   (4 chains of 48)
    {
        const float* rf = wf + n * 192;
        double f0=0, f1=0, f2=0, f3=0;
        #pragma unroll 8
        for (int m = 0; m < 192; m += 4) {
            f0 += x123[p][m]     * (double)rf[m];
            f1 += x123[p][m + 1] * (double)rf[m + 1];
            f2 += x123[p][m + 2] * (double)rf[m + 2];
            f3 += x123[p][m + 3] * (double)rf[m + 3];
        }
        double acc = (double)bf[n] + ((f0 + f1) + (f2 + f3));
        hl[p][n] = acc > 0.0 ? acc : 0.0;
    }
    __syncthreads();

    // phase 2b: Q (sender half of fc1_w), P (receiver half + bias). 4 chains.
    {
        const float* r1 = w1 + n * 128;
        double q0=0, q1=0, p0=(double)b1[n], p1=0;
        #pragma unroll 8
        for (int m = 0; m < HH; m += 2) {
            q0 += hl[p][m]     * (double)r1[m];
            q1 += hl[p][m + 1] * (double)r1[m + 1];
            p0 += hl[p][m]     * (double)r1[64 + m];
            p1 += hl[p][m + 1] * (double)r1[64 + m + 1];
        }
        long base = ((long)b * SS + (s0 + p)) * HH + n;
        Qg[base] = q0 + q1;
        Pg[base] = p0 + p1;
    }
}

// ---------------------------------------------------------------------------
// Kernel 2: edge sign test. 16x16 edge tiles; out[b,i,j] = (j>i) && sign>=0.
//   acc = (b2[0]-b2[1]) + g0 - g1 + sum_k relu(P[i,k]+Q[j,k]) * (w2[0,k]-w2[1,k])
// ---------------------------------------------------------------------------
__global__ __launch_bounds__(256) void edges(
    const double* __restrict__ Qg, const double* __restrict__ Pg,
    const float* __restrict__ w2, const float* __restrict__ b2,
    const float* __restrict__ gum, float* __restrict__ out)
{
    const int b   = blockIdx.y;
    const int tit = blockIdx.x >> 3;    // i-tile
    const int tjt = blockIdx.x & 7;     // j-tile
    const int t   = threadIdx.x;
    const int ti  = t >> 4, tj = t & 15;
    const int i   = tit * 16 + ti;
    const int j   = tjt * 16 + tj;
    float* op = out + ((long)b * SS + i) * SS + j;

    if (tjt < tit) { *op = 0.0f; return; }   // whole tile strictly below diag

    __shared__ double Pl[16][66];
    __shared__ double Ql[16][66];
    __shared__ double dwl[64];

    if (t < 64) dwl[t] = (double)w2[t] - (double)w2[64 + t];
    for (int idx = t; idx < 1024; idx += 256) {
        int r = idx >> 6, c = idx & 63;
        Pl[r][c] = Pg[((long)b * SS + tit * 16 + r) * HH + c];
        Ql[r][c] = Qg[((long)b * SS + tjt * 16 + r) * HH + c];
    }
    __syncthreads();

    if (j <= i) { *op = 0.0f; return; }

    long e = (long)b * SS * SS + (long)i * SS + j;
    double u0 = (double)gum[e * 2 + 0];
    double u1 = (double)gum[e * 2 + 1];
    double base = ((double)b2[0] - (double)b2[1]) - log(-log(u0)) + log(-log(u1));
    double a0 = 0.0, a1 = 0.0;
    #pragma unroll
    for (int k = 0; k < 64; k += 2) {
        double v0 = Pl[ti][k]     + Ql[tj][k];
        double v1 = Pl[ti][k + 1] + Ql[tj][k + 1];
        v0 = v0 > 0.0 ? v0 : 0.0;
        v1 = v1 > 0.0 ? v1 : 0.0;
        a0 += v0 * dwl[k];
        a1 += v1 * dwl[k + 1];
    }
    *op = (base + a0 + a1 >= 0.0) ? 1.0f : 0.0f;
}

extern "C" void kernel_launch(void* const* d_in, const int* in_sizes, int n_in,
                              void* d_out, int out_size, void* d_ws, size_t ws_size,
                              hipStream_t stream) {
    const float* data = (const float*)d_in[0];
    const float* w11  = (const float*)d_in[1];
    const float* b11  = (const float*)d_in[2];
    const float* w12  = (const float*)d_in[3];
    const float* b12  = (const float*)d_in[4];
    const float* w21  = (const float*)d_in[5];
    const float* b21  = (const float*)d_in[6];
    const float* w22  = (const float*)d_in[7];
    const float* b22  = (const float*)d_in[8];
    const float* w31  = (const float*)d_in[9];
    const float* b31  = (const float*)d_in[10];
    const float* wf   = (const float*)d_in[11];
    const float* bf   = (const float*)d_in[12];
    const float* w1   = (const float*)d_in[13];
    const float* b1   = (const float*)d_in[14];
    const float* w2   = (const float*)d_in[15];
    const float* b2   = (const float*)d_in[16];
    const float* gum  = (const float*)d_in[17];
    float* out = (float*)d_out;

    double* Qg = (double*)d_ws;                      // B*S*H doubles = 2 MB
    double* Pg = Qg + (long)BB * SS * HH;            // + 2 MB

    fused_front<<<dim3(SS / STILE, BB), 512, 0, stream>>>(
        data, w11, b11, w12, b12, w21, b21, w22, b22, w31, b31,
        wf, bf, w1, b1, Qg, Pg);
    edges<<<dim3(64, BB), 256, 0, stream>>>(Qg, Pg, w2, b2, gum, out);
}

// Round 3
// 68.650 us; speedup vs baseline: 2.0466x; 1.8475x over previous
//
#include <hip/hip_runtime.h>
#include <math.h>

#define BB   32
#define CIN  16
#define HH   64
#define SS   128
#define NPOS 16

// ws float-region layout (after Qg/Pg doubles): transposed weights [row r][chan n]
//  w11T [16][64]   @ 0        w11T[c*64+k] = w11[k*16+c]
//  w21T [16][64]   @ 1024
//  w12T [192][64]  @ 2048     w12T[r*64+n] = w12[n*192+r]
//  w31T [80][64]   @ 14336
//  w22T [320][64]  @ 19456
//  wfT  [192][64]  @ 39936
//  w1T  [128][64]  @ 52224    (total 60416 floats)
__global__ __launch_bounds__(256) void prep_weights(
    const float* __restrict__ w11, const float* __restrict__ w21,
    const float* __restrict__ w12, const float* __restrict__ w31,
    const float* __restrict__ w22, const float* __restrict__ wf,
    const float* __restrict__ w1,  float* __restrict__ W)
{
    int i = blockIdx.x * 256 + threadIdx.x;
    if (i < 1024)      { int k=i>>4, c=i&15;               W[c*64+k]            = w11[i]; }
    else if (i < 2048) { int j=i-1024;  int k=j>>4,  c=j&15;   W[1024  + c*64+k] = w21[j]; }
    else if (i < 14336){ int j=i-2048;  int n=j/192, r=j%192;  W[2048  + r*64+n] = w12[j]; }
    else if (i < 19456){ int j=i-14336; int n=j/80,  r=j%80;   W[14336 + r*64+n] = w31[j]; }
    else if (i < 39936){ int j=i-19456; int n=j/320, r=j%320;  W[19456 + r*64+n] = w22[j]; }
    else if (i < 52224){ int j=i-39936; int n=j/192, r=j%192;  W[39936 + r*64+n] = wf[j]; }
    else if (i < 60416){ int j=i-52224; int n=j/128, r=j%128;  W[52224 + r*64+n] = w1[j]; }
}

// ---------------------------------------------------------------------------
// fused_front: 256 blocks (one per CU), 1024 threads, 16 positions per block.
// lane n = output channel, wave p = position. Weights staged in a reused
// 80KB LDS float buffer per phase (coalesced loads, lane-contiguous reads);
// data tiles in fp64 LDS with odd strides; fp64 accumulation, split chains.
// ---------------------------------------------------------------------------
__global__ __launch_bounds__(1024, 4) void fused_front(
    const float* __restrict__ x,
    const float* __restrict__ b11, const float* __restrict__ b12,
    const float* __restrict__ b21, const float* __restrict__ b22,
    const float* __restrict__ b31, const float* __restrict__ bf,
    const float* __restrict__ b1,  const float* __restrict__ Wsrc,
    double* __restrict__ Qg, double* __restrict__ Pg)
{
    const int b  = blockIdx.y;
    const int s0 = blockIdx.x * NPOS;
    const int t  = threadIdx.x;

    // column windows relative to s0:
    //  xl  : s0-10 .. s0+25 (36 cols), zero outside [0,S)
    //  t1l : s0-3  .. s0+18 (22 cols), zero (NOT bias) outside [0,S)
    //  t2l : s0-10 .. s0+25 (36 cols)
    __shared__ double xl [CIN][37];
    __shared__ double t1l[HH][23];
    __shared__ double t2l[HH][37];
    __shared__ double x123[NPOS][193];
    __shared__ double hl [NPOS][65];
    __shared__ float  Wbuf[20480];          // 80 KB, reused across phases

    // ---- phase 0: load input slice + w11T/w21T -----------------------------
    if (t < CIN * 36) {
        int c = t / 36, col = t % 36;
        int g = s0 - 10 + col;
        xl[c][col] = (g >= 0 && g < SS) ? (double)x[(b * CIN + c) * SS + g] : 0.0;
    }
    for (int i = t; i < 2048; i += 1024) Wbuf[i] = Wsrc[i];
    __syncthreads();

    // ---- phase A: pointwise convs t1, t2 ----------------------------------
    // items: t1 64ch x 22col = 1408 ; t2 64 x 36 = 2304 ; total 3712
    for (int idx = t; idx < 3712; idx += 1024) {
        if (idx < 1408) {
            int k = idx & 63, col = idx >> 6;            // col 0..21
            int g = s0 - 3 + col;
            double acc = 0.0;
            if (g >= 0 && g < SS) {
                double u0 = (double)b11[k], u1 = 0.0;
                #pragma unroll
                for (int c = 0; c < CIN; c += 2) {
                    u0 += xl[c][col + 7]     * (double)Wbuf[c * 64 + k];
                    u1 += xl[c + 1][col + 7] * (double)Wbuf[(c + 1) * 64 + k];
                }
                acc = u0 + u1;
            }
            t1l[k][col] = acc;
        } else {
            int j = idx - 1408;
            int k = j & 63, col = j >> 6;                // col 0..35
            int g = s0 - 10 + col;
            double acc = 0.0;
            if (g >= 0 && g < SS) {
                double u0 = (double)b21[k], u1 = 0.0;
                #pragma unroll
                for (int c = 0; c < CIN; c += 2) {
                    u0 += xl[c][col]     * (double)Wbuf[1024 + c * 64 + k];
                    u1 += xl[c + 1][col] * (double)Wbuf[1024 + (c + 1) * 64 + k];
                }
                acc = u0 + u1;
            }
            t2l[k][col] = acc;
        }
    }
    __syncthreads();

    const int n = t & 63;        // output channel (lane)
    const int p = t >> 6;        // position (wave) 0..15

    // ---- phase B: load w12T + w31T; compute x1, x3 ------------------------
    for (int i = t; i < 17408; i += 1024) Wbuf[i] = Wsrc[2048 + i];
    __syncthreads();
    {
        double s0a=0, s1a=0, s2a=0, s0b=0, s1b=0, s2b=0;
        #pragma unroll 8
        for (int mm = 0; mm < HH; mm += 2) {
            s0a += t1l[mm][p]         * (double)Wbuf[(mm*3+0)*64 + n];
            s1a += t1l[mm][p + 3]     * (double)Wbuf[(mm*3+1)*64 + n];
            s2a += t1l[mm][p + 6]     * (double)Wbuf[(mm*3+2)*64 + n];
            s0b += t1l[mm+1][p]       * (double)Wbuf[(mm*3+3)*64 + n];
            s1b += t1l[mm+1][p + 3]   * (double)Wbuf[(mm*3+4)*64 + n];
            s2b += t1l[mm+1][p + 6]   * (double)Wbuf[(mm*3+5)*64 + n];
        }
        x123[p][n] = (double)b12[n] + ((s0a + s0b) + (s1a + s1b)) + (s2a + s2b);

        double e0=0, e1=0, e2=0, e3=0, e4=0;
        #pragma unroll
        for (int c = 0; c < CIN; ++c) {
            e0 += xl[c][p + 8]  * (double)Wbuf[12288 + (c*5+0)*64 + n];
            e1 += xl[c][p + 9]  * (double)Wbuf[12288 + (c*5+1)*64 + n];
            e2 += xl[c][p + 10] * (double)Wbuf[12288 + (c*5+2)*64 + n];
            e3 += xl[c][p + 11] * (double)Wbuf[12288 + (c*5+3)*64 + n];
            e4 += xl[c][p + 12] * (double)Wbuf[12288 + (c*5+4)*64 + n];
        }
        x123[p][128 + n] = (double)b31[n] + ((e0 + e1) + (e2 + e3)) + e4;
    }
    __syncthreads();

    // ---- phase C: load w22T; compute x2 -----------------------------------
    for (int i = t; i < 20480; i += 1024) Wbuf[i] = Wsrc[19456 + i];
    __syncthreads();
    {
        double c0=0,c1=0,c2=0,c3=0,c4=0, d0=0,d1=0,d2=0,d3=0,d4=0;
        #pragma unroll 4
        for (int mm = 0; mm < HH; mm += 2) {
            c0 += t2l[mm][p]        * (double)Wbuf[(mm*5+0)*64 + n];
            c1 += t2l[mm][p + 5]    * (double)Wbuf[(mm*5+1)*64 + n];
            c2 += t2l[mm][p + 10]   * (double)Wbuf[(mm*5+2)*64 + n];
            c3 += t2l[mm][p + 15]   * (double)Wbuf[(mm*5+3)*64 + n];
            c4 += t2l[mm][p + 20]   * (double)Wbuf[(mm*5+4)*64 + n];
            d0 += t2l[mm+1][p]      * (double)Wbuf[(mm*5+5)*64 + n];
            d1 += t2l[mm+1][p + 5]  * (double)Wbuf[(mm*5+6)*64 + n];
            d2 += t2l[mm+1][p + 10] * (double)Wbuf[(mm*5+7)*64 + n];
            d3 += t2l[mm+1][p + 15] * (double)Wbuf[(mm*5+8)*64 + n];
            d4 += t2l[mm+1][p + 20] * (double)Wbuf[(mm*5+9)*64 + n];
        }
        x123[p][64 + n] = (double)b22[n]
            + (((c0 + d0) + (c1 + d1)) + ((c2 + d2) + (c3 + d3))) + (c4 + d4);
    }
    __syncthreads();

    // ---- phase D: load wfT; fc_final + relu -> h --------------------------
    for (int i = t; i < 12288; i += 1024) Wbuf[i] = Wsrc[39936 + i];
    __syncthreads();
    {
        double f0=0, f1=0, f2=0, f3=0;
        #pragma unroll 8
        for (int m = 0; m < 192; m += 4) {
            f0 += x123[p][m]     * (double)Wbuf[m*64 + n];
            f1 += x123[p][m + 1] * (double)Wbuf[(m+1)*64 + n];
            f2 += x123[p][m + 2] * (double)Wbuf[(m+2)*64 + n];
            f3 += x123[p][m + 3] * (double)Wbuf[(m+3)*64 + n];
        }
        double acc = (double)bf[n] + ((f0 + f1) + (f2 + f3));
        hl[p][n] = acc > 0.0 ? acc : 0.0;
    }
    __syncthreads();

    // ---- phase E: load w1T; Q, P ------------------------------------------
    for (int i = t; i < 8192; i += 1024) Wbuf[i] = Wsrc[52224 + i];
    __syncthreads();
    {
        double q0=0, q1=0, p0=(double)b1[n], p1=0;
        #pragma unroll 8
        for (int m = 0; m < HH; m += 2) {
            q0 += hl[p][m]     * (double)Wbuf[m*64 + n];
            q1 += hl[p][m + 1] * (double)Wbuf[(m+1)*64 + n];
            p0 += hl[p][m]     * (double)Wbuf[(64+m)*64 + n];
            p1 += hl[p][m + 1] * (double)Wbuf[(64+m+1)*64 + n];
        }
        long base = ((long)b * SS + (s0 + p)) * HH + n;
        Qg[base] = q0 + q1;
        Pg[base] = p0 + p1;
    }
}

// ---------------------------------------------------------------------------
// Kernel 2: edge sign test. out[b,i,j] = (j>i) && sign>=0.
//   acc = (b2[0]-b2[1]) + g0 - g1 + sum_k relu(P[i,k]+Q[j,k]) * (w2[0,k]-w2[1,k])
// ---------------------------------------------------------------------------
__global__ __launch_bounds__(256) void edges(
    const double* __restrict__ Qg, const double* __restrict__ Pg,
    const float* __restrict__ w2, const float* __restrict__ b2,
    const float* __restrict__ gum, float* __restrict__ out)
{
    const int b   = blockIdx.y;
    const int tit = blockIdx.x >> 3;    // i-tile
    const int tjt = blockIdx.x & 7;     // j-tile
    const int t   = threadIdx.x;
    const int ti  = t >> 4, tj = t & 15;
    const int i   = tit * 16 + ti;
    const int j   = tjt * 16 + tj;
    float* op = out + ((long)b * SS + i) * SS + j;

    if (tjt < tit) { *op = 0.0f; return; }   // whole tile strictly below diag

    __shared__ double Pl[16][66];
    __shared__ double Ql[16][66];
    __shared__ double dwl[64];

    if (t < 64) dwl[t] = (double)w2[t] - (double)w2[64 + t];
    for (int idx = t; idx < 1024; idx += 256) {
        int r = idx >> 6, c = idx & 63;
        Pl[r][c] = Pg[((long)b * SS + tit * 16 + r) * HH + c];
        Ql[r][c] = Qg[((long)b * SS + tjt * 16 + r) * HH + c];
    }
    __syncthreads();

    if (j <= i) { *op = 0.0f; return; }

    long e = (long)b * SS * SS + (long)i * SS + j;
    double u0 = (double)gum[e * 2 + 0];
    double u1 = (double)gum[e * 2 + 1];
    double base = ((double)b2[0] - (double)b2[1]) - log(-log(u0)) + log(-log(u1));
    double a0 = 0.0, a1 = 0.0;
    #pragma unroll
    for (int k = 0; k < 64; k += 2) {
        double v0 = Pl[ti][k]     + Ql[tj][k];
        double v1 = Pl[ti][k + 1] + Ql[tj][k + 1];
        v0 = v0 > 0.0 ? v0 : 0.0;
        v1 = v1 > 0.0 ? v1 : 0.0;
        a0 += v0 * dwl[k];
        a1 += v1 * dwl[k + 1];
    }
    *op = (base + a0 + a1 >= 0.0) ? 1.0f : 0.0f;
}

extern "C" void kernel_launch(void* const* d_in, const int* in_sizes, int n_in,
                              void* d_out, int out_size, void* d_ws, size_t ws_size,
                              hipStream_t stream) {
    const float* data = (const float*)d_in[0];
    const float* w11  = (const float*)d_in[1];
    const float* b11  = (const float*)d_in[2];
    const float* w12  = (const float*)d_in[3];
    const float* b12  = (const float*)d_in[4];
    const float* w21  = (const float*)d_in[5];
    const float* b21  = (const float*)d_in[6];
    const float* w22  = (const float*)d_in[7];
    const float* b22  = (const float*)d_in[8];
    const float* w31  = (const float*)d_in[9];
    const float* b31  = (const float*)d_in[10];
    const float* wf   = (const float*)d_in[11];
    const float* bf   = (const float*)d_in[12];
    const float* w1   = (const float*)d_in[13];
    const float* b1   = (const float*)d_in[14];
    const float* w2   = (const float*)d_in[15];
    const float* b2   = (const float*)d_in[16];
    const float* gum  = (const float*)d_in[17];
    float* out = (float*)d_out;

    double* Qg = (double*)d_ws;                      // B*S*H doubles = 2 MB
    double* Pg = Qg + (long)BB * SS * HH;            // + 2 MB
    float*  Wt = (float*)(Pg + (long)BB * SS * HH);  // 60416 floats transposed

    prep_weights<<<236, 256, 0, stream>>>(w11, w21, w12, w31, w22, wf, w1, Wt);
    fused_front<<<dim3(SS / NPOS, BB), 1024, 0, stream>>>(
        data, b11, b12, b21, b22, b31, bf, b1, Wt, Qg, Pg);
    edges<<<dim3(64, BB), 256, 0, stream>>>(Qg, Pg, w2, b2, gum, out);
}

// Round 7
// 51.664 us; speedup vs baseline: 2.7194x; 1.3288x over previous
//
#include <hip/hip_runtime.h>
#include <math.h>

#define BB   32
#define CIN  16
#define HH   64
#define SS   128

typedef double f64x4 __attribute__((ext_vector_type(4)));
#define MFMA64(a,b,c) __builtin_amdgcn_mfma_f64_16x16x4f64((a),(b),(c),0,0,0)

// ---------------------------------------------------------------------------
// Weight prep: one flat f32 stream in MFMA-B orientation [k][n] (n fastest).
//   [0,1024)      w11T[c*64+k]
//   [1024,2048)   w21T[c*64+k]
//   [2048,14336)  w12T  [k=192][64]   (3 chunks of 4096)
//   [14336,34816) w22T  [k=320][64]   (5 chunks)
//   [34816,43008) w31T  [k=128][64]   (2 chunks; rows 80..127 zero-padded)
//   [43008,55296) wfT   [k=192][64]   (3 chunks)
//   [55296,59392) w1T-Q [k=64][64]    (1 chunk)
//   [59392,63488) w1T-P [k=64][64]    (1 chunk)
// ---------------------------------------------------------------------------
__global__ __launch_bounds__(256) void prep_weights(
    const float* __restrict__ w11, const float* __restrict__ w21,
    const float* __restrict__ w12, const float* __restrict__ w22,
    const float* __restrict__ w31, const float* __restrict__ wf,
    const float* __restrict__ w1,  float* __restrict__ W)
{
    int i = blockIdx.x * 256 + threadIdx.x;
    if (i < 1024)       { int k=i>>4, c=i&15;                  W[c*64+k]          = w11[i]; }
    else if (i < 2048)  { int j=i-1024;  int k=j>>4, c=j&15;   W[1024 + c*64+k]   = w21[j]; }
    else if (i < 14336) { int j=i-2048;  int n=j/192, r=j-192*n; W[2048 + r*64+n] = w12[j]; }
    else if (i < 34816) { int j=i-14336; int n=j/320, r=j-320*n; W[14336 + r*64+n]= w22[j]; }
    else if (i < 43008) { int j=i-34816; int r=j>>6, n=j&63;   W[34816 + j] = (r<80)? w31[n*80+r] : 0.f; }
    else if (i < 55296) { int j=i-43008; int n=j/192, r=j-192*n; W[43008 + r*64+n]= wf[j]; }
    else if (i < 59392) { int j=i-55296; int n=j>>6, m=j&63;   W[55296 + m*64+n]  = w1[n*128+m]; }
    else if (i < 63488) { int j=i-59392; int n=j>>6, m=j&63;   W[59392 + m*64+n]  = w1[n*128+64+m]; }
}

// prefetch chunk c (4096 f32) into 16 regs
__device__ __forceinline__ void issue_pf(float* pf, const float* __restrict__ Wsrc,
                                         int c, int t) {
    if (c < 15) {
        const float* s = Wsrc + 2048 + c * 4096 + t;
        #pragma unroll
        for (int q = 0; q < 16; ++q) pf[q] = s[q * 256];
    }
}
// write prefetched chunk into Wf as f64 B-fragments (strides from probe)
__device__ __forceinline__ void commit_pf(const float* pf, double* Wf, int t,
                                          int mB1, int mB2) {
    #pragma unroll
    for (int q = 0; q < 16; ++q) {
        int e = t + 256 * q, k = e >> 6, n = e & 63;
        Wf[((k>>2)<<8) + ((n>>4)<<6) + (k&3)*mB1 + (n&15)*mB2] = (double)pf[q];
    }
}
// 16 MFMA steps (one 64-k chunk), 4 rotating accumulators
__device__ __forceinline__ void mfma_chunk(const double* pA, const double* pB,
                                           f64x4& a0, f64x4& a1, f64x4& a2, f64x4& a3) {
    #pragma unroll
    for (int s = 0; s < 16; s += 4) {
        a0 = MFMA64(pA[(s+0)*64], pB[(s+0)*256], a0);
        a1 = MFMA64(pA[(s+1)*64], pB[(s+1)*256], a1);
        a2 = MFMA64(pA[(s+2)*64], pB[(s+2)*256], a2);
        a3 = MFMA64(pA[(s+3)*64], pB[(s+3)*256], a3);
    }
}

#define RUN_PHASE(NCH, ABASE, ...) do {                                        \
    f64x4 ac0{0,0,0,0}, ac1{0,0,0,0}, ac2{0,0,0,0}, ac3{0,0,0,0};              \
    for (int ch_ = 0; ch_ < (NCH); ++ch_) {                                    \
        commit_pf(pf, Wf, t, mB1, mB2);                                        \
        __syncthreads();                                                       \
        ++cc; issue_pf(pf, Wsrc, cc, t);                                       \
        mfma_chunk((ABASE) + ch_*1024 + lane, Wf + wofs + lane,                \
                   ac0, ac1, ac2, ac3);                                        \
        __syncthreads();                                                       \
    }                                                                          \
    f64x4 acm = (ac0 + ac1) + (ac2 + ac3);                                     \
    __VA_ARGS__                                                                \
} while (0)

// ---------------------------------------------------------------------------
// fused_front: per (batch, 16 positions). 256 thr = 4 waves (wave = N-tile).
// All GEMMs via f64 MFMA 16x16x4. SELF-CALIBRATING layout probe:
//   d1 = MFMA(A=laneid, B=ones):  d1[r] = rowsum of TRUE row held by (lane,r)
//        A-map H  (lane=m+16k): rowsum = 4m+96  (== 0 mod 4)
//        A-map H' (lane=4m+k):  rowsum = 16m+6  (== 2 mod 4)   -> disjoint
//   d2 = MFMA(A=ones, B=laneid): d2[r] = colsum -> B-map + TRUE col.
// So rowi[r]/colj[r] give the exact D mapping with no assumption, and
// mA/mB strides give the A/B fragment storage layout.
// ---------------------------------------------------------------------------
__global__ __launch_bounds__(256, 1) void fused_front(
    const float* __restrict__ x,
    const float* __restrict__ b11, const float* __restrict__ b12,
    const float* __restrict__ b21, const float* __restrict__ b22,
    const float* __restrict__ b31, const float* __restrict__ bf,
    const float* __restrict__ b1,  const float* __restrict__ Wsrc,
    double* __restrict__ Qg, double* __restrict__ Pg)
{
    const int b  = blockIdx.y;
    const int s0 = blockIdx.x * 16;
    const int t  = threadIdx.x;
    const int lane = t & 63, wave = t >> 6, wofs = wave << 6;

    __shared__ float  xl[CIN][37];      // input window s0-10..s0+25 (36 cols)
    __shared__ double t1e[48 * 64];     // conv12 A-frags (k=192); later x123e
    __shared__ double t2e[80 * 64];     // conv22 A-frags (k=320)
    __shared__ double x3e[32 * 64];     // conv31 A-frags; later he
    __shared__ double Wf[4096];         // one 64-k B chunk (aliased f32 wA early)
    __shared__ double x123[16][196];    // conv outputs [p][192]
    double* he = x3e;

    // ---- self-calibrating layout probe (registers only, no sync) ----------
    int rowi[4], colj[4], mA1, mA2, mB1, mB2;
    {
        double lv = (double)lane;
        f64x4 zz{0.0, 0.0, 0.0, 0.0};
        f64x4 d1 = MFMA64(lv, 1.0, zz);   // rowsums of A=laneid
        f64x4 d2 = MFMA64(1.0, lv, zz);   // colsums of B=laneid
        int am = ((((int)d1[0]) & 3) == 0);
        int bm = ((((int)d2[0]) & 3) == 0);
        for (int r = 0; r < 4; ++r) {
            int v1 = (int)d1[r], v2 = (int)d2[r];
            rowi[r] = (am ? (v1 - 96) >> 2 : (v1 - 6) >> 4) & 15;
            colj[r] = (bm ? (v2 - 96) >> 2 : (v2 - 6) >> 4) & 15;
        }
        mA1 = am ? 16 : 1;  mA2 = am ? 1 : 4;
        mB1 = bm ? 16 : 1;  mB2 = bm ? 1 : 4;
    }

    float pf[16];
    int cc = 0;
    issue_pf(pf, Wsrc, 0, t);           // prefetch first weight chunk early

    // ---- stage 0: input window + pointwise weights (wA aliases Wf) --------
    float* wA = (float*)Wf;
    for (int e = t; e < 2048; e += 256) wA[e] = Wsrc[e];
    for (int e = t; e < CIN * 36; e += 256) {
        int c = e / 36, col = e - c * 36;
        int g = s0 - 10 + col;
        xl[c][col] = (g >= 0 && g < SS) ? x[(b * CIN + c) * SS + g] : 0.f;
    }
    __syncthreads();

    // ---- stage A: pointwise convs, written directly as expanded A-frags ---
    for (int e = t; e < 1408; e += 256) {
        int k = e & 63, col = e >> 6;            // col 0..21
        int g = s0 - 3 + col;
        double val = 0.0;
        if (g >= 0 && g < SS) {
            double u0 = (double)b11[k], u1 = 0.0;
            #pragma unroll
            for (int c = 0; c < CIN; c += 2) {
                u0 += (double)xl[c][col + 7]     * (double)wA[c * 64 + k];
                u1 += (double)xl[c + 1][col + 7] * (double)wA[(c + 1) * 64 + k];
            }
            val = u0 + u1;
        }
        #pragma unroll
        for (int tp = 0; tp < 3; ++tp) {
            int p = col - 3 * tp;
            if (p >= 0 && p < 16) {
                int kk = k * 3 + tp;
                t1e[((kk>>2)<<6) + (kk&3)*mA1 + p*mA2] = val;
            }
        }
    }
    for (int e = t; e < 2304; e += 256) {
        int k = e & 63, col = e >> 6;            // col 0..35
        int g = s0 - 10 + col;
        double val = 0.0;
        if (g >= 0 && g < SS) {
            double u0 = (double)b21[k], u1 = 0.0;
            #pragma unroll
            for (int c = 0; c < CIN; c += 2) {
                u0 += (double)xl[c][col]     * (double)wA[1024 + c * 64 + k];
                u1 += (double)xl[c + 1][col] * (double)wA[1024 + (c + 1) * 64 + k];
            }
            val = u0 + u1;
        }
        #pragma unroll
        for (int tp = 0; tp < 5; ++tp) {
            int p = col - 5 * tp;
            if (p >= 0 && p < 16) {
                int kk = k * 5 + tp;
                t2e[((kk>>2)<<6) + (kk&3)*mA1 + p*mA2] = val;
            }
        }
    }
    for (int e = t; e < 2048; e += 256) {
        int p = e & 15, kk = e >> 4;
        double val = 0.0;
        if (kk < 80) { int c = kk / 5, tp = kk - c * 5; val = (double)xl[c][p + 8 + tp]; }
        x3e[((kk>>2)<<6) + (kk&3)*mA1 + p*mA2] = val;
    }
    __syncthreads();

    // ---- conv12 -> x123[:, 0:64) ------------------------------------------
    RUN_PHASE(3, t1e, {
        for (int r = 0; r < 4; ++r) {
            int ch = (wave << 4) + colj[r];
            x123[rowi[r]][ch] = acm[r] + (double)b12[ch];
        }
    });
    // ---- conv22 -> x123[:, 64:128) ----------------------------------------
    RUN_PHASE(5, t2e, {
        for (int r = 0; r < 4; ++r) {
            int ch = (wave << 4) + colj[r];
            x123[rowi[r]][64 + ch] = acm[r] + (double)b22[ch];
        }
    });
    // ---- conv31 -> x123[:, 128:192) ---------------------------------------
    RUN_PHASE(2, x3e, {
        for (int r = 0; r < 4; ++r) {
            int ch = (wave << 4) + colj[r];
            x123[rowi[r]][128 + ch] = acm[r] + (double)b31[ch];
        }
    });
    __syncthreads();
    // ---- repack x123 -> fragment-linear (overlay on t1e) -------------------
    for (int e = t; e < 3072; e += 256) {
        int p = e & 15, k = e >> 4;
        t1e[((k>>2)<<6) + (k&3)*mA1 + p*mA2] = x123[p][k];
    }
    __syncthreads();
    // ---- fc_final + relu -> he (overlay on x3e) ----------------------------
    RUN_PHASE(3, t1e, {
        for (int r = 0; r < 4; ++r) {
            int m = (wave << 4) + colj[r];      // channel = K index of Q/P GEMM
            double v = acm[r] + (double)bf[m];
            he[((m>>2)<<6) + (m&3)*mA1 + rowi[r]*mA2] = v > 0.0 ? v : 0.0;
        }
    });
    // ---- Q = h @ w1[:, :64].T ----------------------------------------------
    RUN_PHASE(1, he, {
        for (int r = 0; r < 4; ++r)
            Qg[((long)b * SS + s0 + rowi[r]) * HH + (wave << 4) + colj[r]] = acm[r];
    });
    // ---- P = h @ w1[:, 64:].T + b1 -----------------------------------------
    RUN_PHASE(1, he, {
        for (int r = 0; r < 4; ++r) {
            int ch = (wave << 4) + colj[r];
            Pg[((long)b * SS + s0 + rowi[r]) * HH + ch] = acm[r] + (double)b1[ch];
        }
    });
}

// ---------------------------------------------------------------------------
// Kernel 2: edge sign test — exact R3 version (known-good).
// ---------------------------------------------------------------------------
__global__ __launch_bounds__(256) void edges(
    const double* __restrict__ Qg, const double* __restrict__ Pg,
    const float* __restrict__ w2, const float* __restrict__ b2,
    const float* __restrict__ gum, float* __restrict__ out)
{
    const int b   = blockIdx.y;
    const int tit = blockIdx.x >> 3;
    const int tjt = blockIdx.x & 7;
    const int t   = threadIdx.x;
    const int ti  = t >> 4, tj = t & 15;
    const int i   = tit * 16 + ti;
    const int j   = tjt * 16 + tj;
    float* op = out + ((long)b * SS + i) * SS + j;

    if (tjt < tit) { *op = 0.0f; return; }

    __shared__ double Pl[16][66];
    __shared__ double Ql[16][66];
    __shared__ double dwl[64];

    if (t < 64) dwl[t] = (double)w2[t] - (double)w2[64 + t];
    for (int idx = t; idx < 1024; idx += 256) {
        int r = idx >> 6, c = idx & 63;
        Pl[r][c] = Pg[((long)b * SS + tit * 16 + r) * HH + c];
        Ql[r][c] = Qg[((long)b * SS + tjt * 16 + r) * HH + c];
    }
    __syncthreads();

    if (j <= i) { *op = 0.0f; return; }

    long e = (long)b * SS * SS + (long)i * SS + j;
    double u0 = (double)gum[e * 2 + 0];
    double u1 = (double)gum[e * 2 + 1];
    double base = ((double)b2[0] - (double)b2[1]) - log(-log(u0)) + log(-log(u1));
    double a0 = 0.0, a1 = 0.0;
    #pragma unroll
    for (int k = 0; k < 64; k += 2) {
        double v0 = Pl[ti][k]     + Ql[tj][k];
        double v1 = Pl[ti][k + 1] + Ql[tj][k + 1];
        v0 = v0 > 0.0 ? v0 : 0.0;
        v1 = v1 > 0.0 ? v1 : 0.0;
        a0 += v0 * dwl[k];
        a1 += v1 * dwl[k + 1];
    }
    *op = (base + a0 + a1 >= 0.0) ? 1.0f : 0.0f;
}

extern "C" void kernel_launch(void* const* d_in, const int* in_sizes, int n_in,
                              void* d_out, int out_size, void* d_ws, size_t ws_size,
                              hipStream_t stream) {
    const float* data = (const float*)d_in[0];
    const float* w11  = (const float*)d_in[1];
    const float* b11  = (const float*)d_in[2];
    const float* w12  = (const float*)d_in[3];
    const float* b12  = (const float*)d_in[4];
    const float* w21  = (const float*)d_in[5];
    const float* b21  = (const float*)d_in[6];
    const float* w22  = (const float*)d_in[7];
    const float* b22  = (const float*)d_in[8];
    const float* w31  = (const float*)d_in[9];
    const float* b31  = (const float*)d_in[10];
    const float* wf   = (const float*)d_in[11];
    const float* bf   = (const float*)d_in[12];
    const float* w1   = (const float*)d_in[13];
    const float* b1   = (const float*)d_in[14];
    const float* w2   = (const float*)d_in[15];
    const float* b2   = (const float*)d_in[16];
    const float* gum  = (const float*)d_in[17];
    float* out = (float*)d_out;

    double* Qg = (double*)d_ws;                      // 2 MB
    double* Pg = Qg + (long)BB * SS * HH;            // 2 MB
    float*  Wt = (float*)(Pg + (long)BB * SS * HH);  // 63488 f32

    prep_weights<<<248, 256, 0, stream>>>(w11, w21, w12, w22, w31, wf, w1, Wt);
    fused_front<<<dim3(8, BB), 256, 0, stream>>>(
        data, b11, b12, b21, b22, b31, bf, b1, Wt, Qg, Pg);
    edges<<<dim3(64, BB), 256, 0, stream>>>(Qg, Pg, w2, b2, gum, out);
}

// Round 8
// 51.388 us; speedup vs baseline: 2.7340x; 1.0054x over previous
//
#include <hip/hip_runtime.h>
#include <math.h>

#define BB   32
#define CIN  16
#define HH   64
#define SS   128

typedef double f64x4 __attribute__((ext_vector_type(4)));
#define MFMA64(a,b,c) __builtin_amdgcn_mfma_f64_16x16x4f64((a),(b),(c),0,0,0)

// ---------------------------------------------------------------------------
// Weight prep (unchanged from R7): flat f32 stream in [k][n] (n fastest).
//   [0,1024) w11T | [1024,2048) w21T | then 15 chunks of 4096:
//   c0-2 w12T(K192) c3-7 w22T(K320) c8-9 w31T(K128,zero-pad) c10-12 wfT(K192)
//   c13 w1T-Q(K64) c14 w1T-P(K64)
// ---------------------------------------------------------------------------
__global__ __launch_bounds__(256) void prep_weights(
    const float* __restrict__ w11, const float* __restrict__ w21,
    const float* __restrict__ w12, const float* __restrict__ w22,
    const float* __restrict__ w31, const float* __restrict__ wf,
    const float* __restrict__ w1,  float* __restrict__ W)
{
    int i = blockIdx.x * 256 + threadIdx.x;
    if (i < 1024)       { int k=i>>4, c=i&15;                  W[c*64+k]          = w11[i]; }
    else if (i < 2048)  { int j=i-1024;  int k=j>>4, c=j&15;   W[1024 + c*64+k]   = w21[j]; }
    else if (i < 14336) { int j=i-2048;  int n=j/192, r=j-192*n; W[2048 + r*64+n] = w12[j]; }
    else if (i < 34816) { int j=i-14336; int n=j/320, r=j-320*n; W[14336 + r*64+n]= w22[j]; }
    else if (i < 43008) { int j=i-34816; int r=j>>6, n=j&63;   W[34816 + j] = (r<80)? w31[n*80+r] : 0.f; }
    else if (i < 55296) { int j=i-43008; int n=j/192, r=j-192*n; W[43008 + r*64+n]= wf[j]; }
    else if (i < 59392) { int j=i-55296; int n=j>>6, m=j&63;   W[55296 + m*64+n]  = w1[n*128+m]; }
    else if (i < 63488) { int j=i-59392; int n=j>>6, m=j&63;   W[59392 + m*64+n]  = w1[n*128+64+m]; }
}

// load chunk c's 16 per-lane B values (f32) into regs; Bb is per-lane base
__device__ __forceinline__ void loadB(float* dst, const float* __restrict__ Bb, int c) {
    const float* s = Bb + c * 4096;
    #pragma unroll
    for (int q = 0; q < 16; ++q) dst[q] = s[q * 256];
}
// 16 MFMA steps of one 64-K chunk; A from LDS fragments, B from regs (exact cvt)
__device__ __forceinline__ void mfma_chunk(const double* pA, const float* cb,
                                           f64x4& a0, f64x4& a1, f64x4& a2, f64x4& a3) {
    #pragma unroll
    for (int s = 0; s < 16; s += 4) {
        a0 = MFMA64(pA[(s+0)*64], (double)cb[s+0], a0);
        a1 = MFMA64(pA[(s+1)*64], (double)cb[s+1], a1);
        a2 = MFMA64(pA[(s+2)*64], (double)cb[s+2], a2);
        a3 = MFMA64(pA[(s+3)*64], (double)cb[s+3], a3);
    }
}

// ---------------------------------------------------------------------------
// fused_front v3: 4 waves, NO per-chunk barriers (5 total). B operands stream
// global->register (double-buffered); A fragments in LDS (R7-proven layouts,
// self-calibrating probe for D/A/B lane mappings).
// ---------------------------------------------------------------------------
__global__ __launch_bounds__(256, 1) void fused_front(
    const float* __restrict__ x,
    const float* __restrict__ b11, const float* __restrict__ b12,
    const float* __restrict__ b21, const float* __restrict__ b22,
    const float* __restrict__ b31, const float* __restrict__ bf,
    const float* __restrict__ b1,  const float* __restrict__ Wsrc,
    double* __restrict__ Qg, double* __restrict__ Pg)
{
    const int b  = blockIdx.y;
    const int s0 = blockIdx.x * 16;
    const int t  = threadIdx.x;
    const int lane = t & 63, wave = t >> 6;

    __shared__ float  xl[CIN][37];      // input window s0-10..s0+25
    __shared__ float  wA[2048];         // w11T/w21T
    __shared__ double t1e[48 * 64];     // conv12 A-frags; later fc A-frags
    __shared__ double t2e[80 * 64];     // conv22 A-frags
    __shared__ double x3e[32 * 64];     // conv31 A-frags; later he
    __shared__ double x123[16][196];
    double* he = x3e;

    // ---- self-calibrating layout probe (registers only) -------------------
    int rowi[4], colj[4], mA1, mA2, bn, bkk;
    {
        double lv = (double)lane;
        f64x4 zz{0.0, 0.0, 0.0, 0.0};
        f64x4 d1 = MFMA64(lv, 1.0, zz);   // rowsums of A=laneid
        f64x4 d2 = MFMA64(1.0, lv, zz);   // colsums of B=laneid
        int am = ((((int)d1[0]) & 3) == 0);
        int bm = ((((int)d2[0]) & 3) == 0);
        for (int r = 0; r < 4; ++r) {
            int v1 = (int)d1[r], v2 = (int)d2[r];
            rowi[r] = (am ? (v1 - 96) >> 2 : (v1 - 6) >> 4) & 15;
            colj[r] = (bm ? (v2 - 96) >> 2 : (v2 - 6) >> 4) & 15;
        }
        mA1 = am ? 16 : 1;  mA2 = am ? 1 : 4;
        bn  = bm ? (lane & 15) : (lane >> 2);   // B: lane holds B[k][n]
        bkk = bm ? (lane >> 4) : (lane & 3);
    }
    const float* Bb = Wsrc + 2048 + bkk * 64 + (wave << 4) + bn;

    float bufa[16], bufb[16];
    loadB(bufa, Bb, 0);                 // chunk 0 in flight early

    // ---- stage 0: input window + pointwise weights -------------------------
    for (int e = t; e < 2048; e += 256) wA[e] = Wsrc[e];
    for (int e = t; e < CIN * 36; e += 256) {
        int c = e / 36, col = e - c * 36;
        int g = s0 - 10 + col;
        xl[c][col] = (g >= 0 && g < SS) ? x[(b * CIN + c) * SS + g] : 0.f;
    }
    __syncthreads();                                            // S1

    // ---- stage A: pointwise convs -> expanded A-frags (R7-identical) -------
    for (int e = t; e < 1408; e += 256) {
        int k = e & 63, col = e >> 6;            // col 0..21
        int g = s0 - 3 + col;
        double val = 0.0;
        if (g >= 0 && g < SS) {
            double u0 = (double)b11[k], u1 = 0.0;
            #pragma unroll
            for (int c = 0; c < CIN; c += 2) {
                u0 += (double)xl[c][col + 7]     * (double)wA[c * 64 + k];
                u1 += (double)xl[c + 1][col + 7] * (double)wA[(c + 1) * 64 + k];
            }
            val = u0 + u1;
        }
        #pragma unroll
        for (int tp = 0; tp < 3; ++tp) {
            int p = col - 3 * tp;
            if (p >= 0 && p < 16) {
                int kk = k * 3 + tp;
                t1e[((kk>>2)<<6) + (kk&3)*mA1 + p*mA2] = val;
            }
        }
    }
    for (int e = t; e < 2304; e += 256) {
        int k = e & 63, col = e >> 6;            // col 0..35
        int g = s0 - 10 + col;
        double val = 0.0;
        if (g >= 0 && g < SS) {
            double u0 = (double)b21[k], u1 = 0.0;
            #pragma unroll
            for (int c = 0; c < CIN; c += 2) {
                u0 += (double)xl[c][col]     * (double)wA[1024 + c * 64 + k];
                u1 += (double)xl[c + 1][col] * (double)wA[1024 + (c + 1) * 64 + k];
            }
            val = u0 + u1;
        }
        #pragma unroll
        for (int tp = 0; tp < 5; ++tp) {
            int p = col - 5 * tp;
            if (p >= 0 && p < 16) {
                int kk = k * 5 + tp;
                t2e[((kk>>2)<<6) + (kk&3)*mA1 + p*mA2] = val;
            }
        }
    }
    for (int e = t; e < 2048; e += 256) {
        int p = e & 15, kk = e >> 4;
        double val = 0.0;
        if (kk < 80) { int c = kk / 5, tp = kk - c * 5; val = (double)xl[c][p + 8 + tp]; }
        x3e[((kk>>2)<<6) + (kk&3)*mA1 + p*mA2] = val;
    }
    __syncthreads();                                            // S2

    // ---- conv12 (chunks 0-2) -> x123[:,0:64) -------------------------------
    {
        f64x4 a0{0,0,0,0}, a1{0,0,0,0}, a2{0,0,0,0}, a3{0,0,0,0};
        loadB(bufb, Bb, 1);  mfma_chunk(t1e + lane,        bufa, a0,a1,a2,a3);
        loadB(bufa, Bb, 2);  mfma_chunk(t1e + 1024 + lane, bufb, a0,a1,a2,a3);
        loadB(bufb, Bb, 3);  mfma_chunk(t1e + 2048 + lane, bufa, a0,a1,a2,a3);
        f64x4 acm = (a0 + a1) + (a2 + a3);
        for (int r = 0; r < 4; ++r) {
            int ch = (wave << 4) + colj[r];
            x123[rowi[r]][ch] = acm[r] + (double)b12[ch];
        }
    }
    // ---- conv22 (chunks 3-7) -> x123[:,64:128) -----------------------------
    {
        f64x4 a0{0,0,0,0}, a1{0,0,0,0}, a2{0,0,0,0}, a3{0,0,0,0};
        loadB(bufa, Bb, 4);  mfma_chunk(t2e + lane,        bufb, a0,a1,a2,a3);
        loadB(bufb, Bb, 5);  mfma_chunk(t2e + 1024 + lane, bufa, a0,a1,a2,a3);
        loadB(bufa, Bb, 6);  mfma_chunk(t2e + 2048 + lane, bufb, a0,a1,a2,a3);
        loadB(bufb, Bb, 7);  mfma_chunk(t2e + 3072 + lane, bufa, a0,a1,a2,a3);
        loadB(bufa, Bb, 8);  mfma_chunk(t2e + 4096 + lane, bufb, a0,a1,a2,a3);
        f64x4 acm = (a0 + a1) + (a2 + a3);
        for (int r = 0; r < 4; ++r) {
            int ch = (wave << 4) + colj[r];
            x123[rowi[r]][64 + ch] = acm[r] + (double)b22[ch];
        }
    }
    // ---- conv31 (chunks 8-9) -> x123[:,128:192) ----------------------------
    {
        f64x4 a0{0,0,0,0}, a1{0,0,0,0}, a2{0,0,0,0}, a3{0,0,0,0};
        loadB(bufb, Bb, 9);  mfma_chunk(x3e + lane,        bufa, a0,a1,a2,a3);
        loadB(bufa, Bb, 10); mfma_chunk(x3e + 1024 + lane, bufb, a0,a1,a2,a3);
        f64x4 acm = (a0 + a1) + (a2 + a3);
        for (int r = 0; r < 4; ++r) {
            int ch = (wave << 4) + colj[r];
            x123[rowi[r]][128 + ch] = acm[r] + (double)b31[ch];
        }
    }
    __syncthreads();                                            // S3
    // ---- repack x123 -> fragment-linear (overlay t1e) ----------------------
    for (int e = t; e < 3072; e += 256) {
        int p = e & 15, k = e >> 4;
        t1e[((k>>2)<<6) + (k&3)*mA1 + p*mA2] = x123[p][k];
    }
    __syncthreads();                                            // S4
    // ---- fc_final + relu -> he (chunks 10-12) ------------------------------
    {
        f64x4 a0{0,0,0,0}, a1{0,0,0,0}, a2{0,0,0,0}, a3{0,0,0,0};
        loadB(bufb, Bb, 11); mfma_chunk(t1e + lane,        bufa, a0,a1,a2,a3);
        loadB(bufa, Bb, 12); mfma_chunk(t1e + 1024 + lane, bufb, a0,a1,a2,a3);
        loadB(bufb, Bb, 13); mfma_chunk(t1e + 2048 + lane, bufa, a0,a1,a2,a3);
        f64x4 acm = (a0 + a1) + (a2 + a3);
        for (int r = 0; r < 4; ++r) {
            int m = (wave << 4) + colj[r];      // channel = K index of Q/P GEMM
            double v = acm[r] + (double)bf[m];
            he[((m>>2)<<6) + (m&3)*mA1 + rowi[r]*mA2] = v > 0.0 ? v : 0.0;
        }
    }
    __syncthreads();                                            // S5
    // ---- Q (chunk 13) -------------------------------------------------------
    {
        f64x4 a0{0,0,0,0}, a1{0,0,0,0}, a2{0,0,0,0}, a3{0,0,0,0};
        loadB(bufa, Bb, 14); mfma_chunk(he + lane, bufb, a0,a1,a2,a3);
        f64x4 acm = (a0 + a1) + (a2 + a3);
        for (int r = 0; r < 4; ++r)
            Qg[((long)b * SS + s0 + rowi[r]) * HH + (wave << 4) + colj[r]] = acm[r];
    }
    // ---- P (chunk 14) -------------------------------------------------------
    {
        f64x4 a0{0,0,0,0}, a1{0,0,0,0}, a2{0,0,0,0}, a3{0,0,0,0};
        mfma_chunk(he + lane, bufa, a0,a1,a2,a3);
        f64x4 acm = (a0 + a1) + (a2 + a3);
        for (int r = 0; r < 4; ++r) {
            int ch = (wave << 4) + colj[r];
            Pg[((long)b * SS + s0 + rowi[r]) * HH + ch] = acm[r] + (double)b1[ch];
        }
    }
}

// ---------------------------------------------------------------------------
// Kernel 2: edge sign test, f32 fast path + exact f64 recompute for edges
// with |acc| < 3e-3 (f32 error bound ~5e-5; deterministic per input).
// ---------------------------------------------------------------------------
__global__ __launch_bounds__(256) void edges(
    const double* __restrict__ Qg, const double* __restrict__ Pg,
    const float* __restrict__ w2, const float* __restrict__ b2,
    const float* __restrict__ gum, float* __restrict__ out)
{
    const int b   = blockIdx.y;
    const int tit = blockIdx.x >> 3;
    const int tjt = blockIdx.x & 7;
    const int t   = threadIdx.x;
    const int ti  = t >> 4, tj = t & 15;
    const int i   = tit * 16 + ti;
    const int j   = tjt * 16 + tj;
    float* op = out + ((long)b * SS + i) * SS + j;

    if (tjt < tit) { *op = 0.0f; return; }

    __shared__ float Plf[16][68];   // stride 68 f32 = 272B -> 16B aligned rows
    __shared__ float Qlf[16][68];
    __shared__ float dwl[64];

    if (t < 64) dwl[t] = w2[t] - w2[64 + t];
    for (int idx = t; idx < 1024; idx += 256) {
        int r = idx >> 6, c = idx & 63;
        Plf[r][c] = (float)Pg[((long)b * SS + tit * 16 + r) * HH + c];
        Qlf[r][c] = (float)Qg[((long)b * SS + tjt * 16 + r) * HH + c];
    }
    __syncthreads();

    if (j <= i) { *op = 0.0f; return; }

    long e = (long)b * SS * SS + (long)i * SS + j;
    const float2 uv = *(const float2*)(gum + e * 2);
    float basef = (b2[0] - b2[1]) - logf(-logf(uv.x)) + logf(-logf(uv.y));

    const float2* Pr = (const float2*)(&Plf[ti][0]);
    const float2* Qr = (const float2*)(&Qlf[tj][0]);
    const float2* Dr = (const float2*)dwl;
    float s0 = 0.f, s1 = 0.f;
    #pragma unroll
    for (int k2 = 0; k2 < 32; ++k2) {
        float2 pv = Pr[k2], qv = Qr[k2], dv = Dr[k2];
        float v0 = pv.x + qv.x; v0 = v0 > 0.f ? v0 : 0.f;
        float v1 = pv.y + qv.y; v1 = v1 > 0.f ? v1 : 0.f;
        s0 += v0 * dv.x; s1 += v1 * dv.y;
    }
    float tot = basef + s0 + s1;

    if (fabsf(tot) < 3e-3f) {          // exact f64 recompute (rare)
        const double* Prd = Pg + ((long)b * SS + i) * HH;
        const double* Qrd = Qg + ((long)b * SS + j) * HH;
        double acc = (double)b2[0] - (double)b2[1]
                   - log(-log((double)uv.x)) + log(-log((double)uv.y));
        for (int k = 0; k < 64; ++k) {
            double v = Prd[k] + Qrd[k];
            if (v > 0.0) acc += v * ((double)w2[k] - (double)w2[64 + k]);
        }
        *op = (acc >= 0.0) ? 1.0f : 0.0f;
    } else {
        *op = (tot >= 0.f) ? 1.0f : 0.0f;
    }
}

extern "C" void kernel_launch(void* const* d_in, const int* in_sizes, int n_in,
                              void* d_out, int out_size, void* d_ws, size_t ws_size,
                              hipStream_t stream) {
    const float* data = (const float*)d_in[0];
    const float* w11  = (const float*)d_in[1];
    const float* b11  = (const float*)d_in[2];
    const float* w12  = (const float*)d_in[3];
    const float* b12  = (const float*)d_in[4];
    const float* w21  = (const float*)d_in[5];
    const float* b21  = (const float*)d_in[6];
    const float* w22  = (const float*)d_in[7];
    const float* b22  = (const float*)d_in[8];
    const float* w31  = (const float*)d_in[9];
    const float* b31  = (const float*)d_in[10];
    const float* wf   = (const float*)d_in[11];
    const float* bf   = (const float*)d_in[12];
    const float* w1   = (const float*)d_in[13];
    const float* b1   = (const float*)d_in[14];
    const float* w2   = (const float*)d_in[15];
    const float* b2   = (const float*)d_in[16];
    const float* gum  = (const float*)d_in[17];
    float* out = (float*)d_out;

    double* Qg = (double*)d_ws;                      // 2 MB
    double* Pg = Qg + (long)BB * SS * HH;            // 2 MB
    float*  Wt = (float*)(Pg + (long)BB * SS * HH);  // 63488 f32

    prep_weights<<<248, 256, 0, stream>>>(w11, w21, w12, w22, w31, wf, w1, Wt);
    fused_front<<<dim3(8, BB), 256, 0, stream>>>(
        data, b11, b12, b21, b22, b31, bf, b1, Wt, Qg, Pg);
    edges<<<dim3(64, BB), 256, 0, stream>>>(Qg, Pg, w2, b2, gum, out);
}

// Round 9
// 49.210 us; speedup vs baseline: 2.8551x; 1.0443x over previous
//
#include <hip/hip_runtime.h>
#include <math.h>

#define BB   32
#define CIN  16
#define HH   64
#define SS   128

typedef double f64x4 __attribute__((ext_vector_type(4)));
#define MFMA64(a,b,c) __builtin_amdgcn_mfma_f64_16x16x4f64((a),(b),(c),0,0,0)

// ---------------------------------------------------------------------------
// Weight prep (unchanged): flat f32 stream in [k][n] (n fastest).
//   [0,1024) w11T | [1024,2048) w21T | then 15 chunks of 4096:
//   c0-2 w12T(K192) c3-7 w22T(K320) c8-9 w31T(K128,zero-pad) c10-12 wfT(K192)
//   c13 w1T-Q(K64) c14 w1T-P(K64)
// ---------------------------------------------------------------------------
__global__ __launch_bounds__(256) void prep_weights(
    const float* __restrict__ w11, const float* __restrict__ w21,
    const float* __restrict__ w12, const float* __restrict__ w22,
    const float* __restrict__ w31, const float* __restrict__ wf,
    const float* __restrict__ w1,  float* __restrict__ W)
{
    int i = blockIdx.x * 256 + threadIdx.x;
    if (i < 1024)       { int k=i>>4, c=i&15;                  W[c*64+k]          = w11[i]; }
    else if (i < 2048)  { int j=i-1024;  int k=j>>4, c=j&15;   W[1024 + c*64+k]   = w21[j]; }
    else if (i < 14336) { int j=i-2048;  int n=j/192, r=j-192*n; W[2048 + r*64+n] = w12[j]; }
    else if (i < 34816) { int j=i-14336; int n=j/320, r=j-320*n; W[14336 + r*64+n]= w22[j]; }
    else if (i < 43008) { int j=i-34816; int r=j>>6, n=j&63;   W[34816 + j] = (r<80)? w31[n*80+r] : 0.f; }
    else if (i < 55296) { int j=i-43008; int n=j/192, r=j-192*n; W[43008 + r*64+n]= wf[j]; }
    else if (i < 59392) { int j=i-55296; int n=j>>6, m=j&63;   W[55296 + m*64+n]  = w1[n*128+m]; }
    else if (i < 63488) { int j=i-59392; int n=j>>6, m=j&63;   W[59392 + m*64+n]  = w1[n*128+64+m]; }
}

// load 8 (or 2) per-lane B values of chunk c, starting at step koff
__device__ __forceinline__ void loadB8(float* dst, const float* __restrict__ Bb,
                                       int c, int koff) {
    const float* s = Bb + c * 4096 + koff * 256;
    #pragma unroll
    for (int q = 0; q < 8; ++q) dst[q] = s[q * 256];
}
__device__ __forceinline__ void loadB2(float* dst, const float* __restrict__ Bb,
                                       int c, int koff) {
    const float* s = Bb + c * 4096 + koff * 256;
    dst[0] = s[0]; dst[1] = s[256];
}
// 8 (or 2) MFMA steps at absolute step offset boff within the chunk
__device__ __forceinline__ void mfma8(const double* pA, const float* cb, int boff,
                                      f64x4& a0, f64x4& a1, f64x4& a2, f64x4& a3) {
    #pragma unroll
    for (int s = 0; s < 8; s += 4) {
        a0 = MFMA64(pA[(boff+s+0)*64], (double)cb[s+0], a0);
        a1 = MFMA64(pA[(boff+s+1)*64], (double)cb[s+1], a1);
        a2 = MFMA64(pA[(boff+s+2)*64], (double)cb[s+2], a2);
        a3 = MFMA64(pA[(boff+s+3)*64], (double)cb[s+3], a3);
    }
}
__device__ __forceinline__ void mfma2(const double* pA, const float* cb, int boff,
                                      f64x4& a0, f64x4& a1) {
    a0 = MFMA64(pA[(boff+0)*64], (double)cb[0], a0);
    a1 = MFMA64(pA[(boff+1)*64], (double)cb[1], a1);
}

// ---------------------------------------------------------------------------
// fused_front v4: 512 thr = 8 waves = (4 N-tiles) x (2 K-halves). Each chunk's
// 16 MFMA steps split 8/8 across the K-half waves -> 2 waves/SIMD issuing
// MFMAs concurrently (double the issue overlap of v3). Per phase, kh=1 waves
// write their partial acc to LDS; kh=0 waves add + epilogue.
// ---------------------------------------------------------------------------
__global__ __launch_bounds__(512, 1) void fused_front(
    const float* __restrict__ x,
    const float* __restrict__ b11, const float* __restrict__ b12,
    const float* __restrict__ b21, const float* __restrict__ b22,
    const float* __restrict__ b31, const float* __restrict__ bf,
    const float* __restrict__ b1,  const float* __restrict__ Wsrc,
    double* __restrict__ Qg, double* __restrict__ Pg)
{
    const int b  = blockIdx.y;
    const int s0 = blockIdx.x * 16;
    const int t  = threadIdx.x;
    const int lane = t & 63, wave = t >> 6;
    const int wv = wave & 3;            // N-tile (channels 16wv..16wv+15)
    const int kh = wave >> 2;           // K-half (steps 8kh..8kh+7 per chunk)
    const int kh8 = kh << 3, kh2 = kh << 1;

    __shared__ float  xl[CIN][37];      // input window s0-10..s0+25
    __shared__ float  wA[2048];         // w11T/w21T
    __shared__ double t1e[48 * 64];     // conv12 A-frags; later fc A-frags
    __shared__ double t2e[80 * 64];     // conv22 A-frags
    __shared__ double x3e[32 * 64];     // conv31 A-frags; later he
    __shared__ double x123[16][196];
    __shared__ double part[4][4][64];   // kh=1 partial acc [r][wv][lane]
    double* he = x3e;

    // ---- self-calibrating layout probe (registers only) -------------------
    int rowi[4], colj[4], mA1, mA2, bn, bkk;
    {
        double lv = (double)lane;
        f64x4 zz{0.0, 0.0, 0.0, 0.0};
        f64x4 d1 = MFMA64(lv, 1.0, zz);   // rowsums of A=laneid
        f64x4 d2 = MFMA64(1.0, lv, zz);   // colsums of B=laneid
        int am = ((((int)d1[0]) & 3) == 0);
        int bm = ((((int)d2[0]) & 3) == 0);
        for (int r = 0; r < 4; ++r) {
            int v1 = (int)d1[r], v2 = (int)d2[r];
            rowi[r] = (am ? (v1 - 96) >> 2 : (v1 - 6) >> 4) & 15;
            colj[r] = (bm ? (v2 - 96) >> 2 : (v2 - 6) >> 4) & 15;
        }
        mA1 = am ? 16 : 1;  mA2 = am ? 1 : 4;
        bn  = bm ? (lane & 15) : (lane >> 2);   // B: lane holds B[k][n]
        bkk = bm ? (lane >> 4) : (lane & 3);
    }
    const float* Bb = Wsrc + 2048 + bkk * 64 + (wv << 4) + bn;

    float bufa[8], bufb[8];
    loadB8(bufa, Bb, 0, kh8);           // chunk 0 (this wave's half) in flight

    // ---- stage 0: input window + pointwise weights -------------------------
    for (int e = t; e < 2048; e += 512) wA[e] = Wsrc[e];
    for (int e = t; e < CIN * 36; e += 512) {
        int c = e / 36, col = e - c * 36;
        int g = s0 - 10 + col;
        xl[c][col] = (g >= 0 && g < SS) ? x[(b * CIN + c) * SS + g] : 0.f;
    }
    __syncthreads();                                            // S1

    // ---- stage A: pointwise convs -> expanded A-frags ----------------------
    for (int e = t; e < 1408; e += 512) {
        int k = e & 63, col = e >> 6;            // col 0..21
        int g = s0 - 3 + col;
        double val = 0.0;
        if (g >= 0 && g < SS) {
            double u0 = (double)b11[k], u1 = 0.0;
            #pragma unroll
            for (int c = 0; c < CIN; c += 2) {
                u0 += (double)xl[c][col + 7]     * (double)wA[c * 64 + k];
                u1 += (double)xl[c + 1][col + 7] * (double)wA[(c + 1) * 64 + k];
            }
            val = u0 + u1;
        }
        #pragma unroll
        for (int tp = 0; tp < 3; ++tp) {
            int p = col - 3 * tp;
            if (p >= 0 && p < 16) {
                int kk = k * 3 + tp;
                t1e[((kk>>2)<<6) + (kk&3)*mA1 + p*mA2] = val;
            }
        }
    }
    for (int e = t; e < 2304; e += 512) {
        int k = e & 63, col = e >> 6;            // col 0..35
        int g = s0 - 10 + col;
        double val = 0.0;
        if (g >= 0 && g < SS) {
            double u0 = (double)b21[k], u1 = 0.0;
            #pragma unroll
            for (int c = 0; c < CIN; c += 2) {
                u0 += (double)xl[c][col]     * (double)wA[1024 + c * 64 + k];
                u1 += (double)xl[c + 1][col] * (double)wA[1024 + (c + 1) * 64 + k];
            }
            val = u0 + u1;
        }
        #pragma unroll
        for (int tp = 0; tp < 5; ++tp) {
            int p = col - 5 * tp;
            if (p >= 0 && p < 16) {
                int kk = k * 5 + tp;
                t2e[((kk>>2)<<6) + (kk&3)*mA1 + p*mA2] = val;
            }
        }
    }
    for (int e = t; e < 2048; e += 512) {
        int p = e & 15, kk = e >> 4;
        double val = 0.0;
        if (kk < 80) { int c = kk / 5, tp = kk - c * 5; val = (double)xl[c][p + 8 + tp]; }
        x3e[((kk>>2)<<6) + (kk&3)*mA1 + p*mA2] = val;
    }
    __syncthreads();                                            // S2

    // ---- conv12 (chunks 0-2) -> x123[:,0:64) -------------------------------
    {
        f64x4 a0{0,0,0,0}, a1{0,0,0,0}, a2{0,0,0,0}, a3{0,0,0,0};
        loadB8(bufb, Bb, 1, kh8);  mfma8(t1e + lane,        bufa, kh8, a0,a1,a2,a3);
        loadB8(bufa, Bb, 2, kh8);  mfma8(t1e + 1024 + lane, bufb, kh8, a0,a1,a2,a3);
        loadB8(bufb, Bb, 3, kh8);  mfma8(t1e + 2048 + lane, bufa, kh8, a0,a1,a2,a3);
        f64x4 acm = (a0 + a1) + (a2 + a3);
        if (kh) { for (int r = 0; r < 4; ++r) part[r][wv][lane] = acm[r]; }
        __syncthreads();
        if (!kh) {
            for (int r = 0; r < 4; ++r) {
                int ch = (wv << 4) + colj[r];
                x123[rowi[r]][ch] = acm[r] + part[r][wv][lane] + (double)b12[ch];
            }
        }
        __syncthreads();
    }
    // ---- conv22 (chunks 3-7) -> x123[:,64:128) -----------------------------
    {
        f64x4 a0{0,0,0,0}, a1{0,0,0,0}, a2{0,0,0,0}, a3{0,0,0,0};
        loadB8(bufa, Bb, 4, kh8);  mfma8(t2e + lane,        bufb, kh8, a0,a1,a2,a3);
        loadB8(bufb, Bb, 5, kh8);  mfma8(t2e + 1024 + lane, bufa, kh8, a0,a1,a2,a3);
        loadB8(bufa, Bb, 6, kh8);  mfma8(t2e + 2048 + lane, bufb, kh8, a0,a1,a2,a3);
        loadB8(bufb, Bb, 7, kh8);  mfma8(t2e + 3072 + lane, bufa, kh8, a0,a1,a2,a3);
        loadB8(bufa, Bb, 8, kh8);  mfma8(t2e + 4096 + lane, bufb, kh8, a0,a1,a2,a3);
        f64x4 acm = (a0 + a1) + (a2 + a3);
        if (kh) { for (int r = 0; r < 4; ++r) part[r][wv][lane] = acm[r]; }
        __syncthreads();
        if (!kh) {
            for (int r = 0; r < 4; ++r) {
                int ch = (wv << 4) + colj[r];
                x123[rowi[r]][64 + ch] = acm[r] + part[r][wv][lane] + (double)b22[ch];
            }
        }
        __syncthreads();
    }
    // ---- conv31 (chunk 8 + chunk 9[k<16]) -> x123[:,128:192) ---------------
    {
        f64x4 a0{0,0,0,0}, a1{0,0,0,0}, a2{0,0,0,0}, a3{0,0,0,0};
        loadB2(bufb, Bb, 9, kh2);  mfma8(x3e + lane,        bufa, kh8, a0,a1,a2,a3);
        loadB8(bufa, Bb, 10, kh8); mfma2(x3e + 1024 + lane, bufb, kh2, a0,a1);
        f64x4 acm = (a0 + a1) + (a2 + a3);
        if (kh) { for (int r = 0; r < 4; ++r) part[r][wv][lane] = acm[r]; }
        __syncthreads();
        if (!kh) {
            for (int r = 0; r < 4; ++r) {
                int ch = (wv << 4) + colj[r];
                x123[rowi[r]][128 + ch] = acm[r] + part[r][wv][lane] + (double)b31[ch];
            }
        }
        __syncthreads();
    }
    // ---- repack x123 -> fragment-linear (overlay t1e) ----------------------
    for (int e = t; e < 3072; e += 512) {
        int p = e & 15, k = e >> 4;
        t1e[((k>>2)<<6) + (k&3)*mA1 + p*mA2] = x123[p][k];
    }
    __syncthreads();                                            // S4
    // ---- fc_final + relu -> he (chunks 10-12) ------------------------------
    {
        f64x4 a0{0,0,0,0}, a1{0,0,0,0}, a2{0,0,0,0}, a3{0,0,0,0};
        loadB8(bufb, Bb, 11, kh8); mfma8(t1e + lane,        bufa, kh8, a0,a1,a2,a3);
        loadB8(bufa, Bb, 12, kh8); mfma8(t1e + 1024 + lane, bufb, kh8, a0,a1,a2,a3);
        loadB8(bufb, Bb, 13, kh8); mfma8(t1e + 2048 + lane, bufa, kh8, a0,a1,a2,a3);
        f64x4 acm = (a0 + a1) + (a2 + a3);
        if (kh) { for (int r = 0; r < 4; ++r) part[r][wv][lane] = acm[r]; }
        __syncthreads();
        if (!kh) {
            for (int r = 0; r < 4; ++r) {
                int m = (wv << 4) + colj[r];    // channel = K index of Q/P GEMM
                double v = acm[r] + part[r][wv][lane] + (double)bf[m];
                he[((m>>2)<<6) + (m&3)*mA1 + rowi[r]*mA2] = v > 0.0 ? v : 0.0;
            }
        }
        __syncthreads();
    }
    // ---- Q (chunk 13) ------------------------------------------------------
    {
        f64x4 a0{0,0,0,0}, a1{0,0,0,0}, a2{0,0,0,0}, a3{0,0,0,0};
        loadB8(bufa, Bb, 14, kh8); mfma8(he + lane, bufb, kh8, a0,a1,a2,a3);
        f64x4 acm = (a0 + a1) + (a2 + a3);
        if (kh) { for (int r = 0; r < 4; ++r) part[r][wv][lane] = acm[r]; }
        __syncthreads();
        if (!kh) {
            for (int r = 0; r < 4; ++r)
                Qg[((long)b * SS + s0 + rowi[r]) * HH + (wv << 4) + colj[r]]
                    = acm[r] + part[r][wv][lane];
        }
        __syncthreads();
    }
    // ---- P (chunk 14) ------------------------------------------------------
    {
        f64x4 a0{0,0,0,0}, a1{0,0,0,0}, a2{0,0,0,0}, a3{0,0,0,0};
        mfma8(he + lane, bufa, kh8, a0,a1,a2,a3);
        f64x4 acm = (a0 + a1) + (a2 + a3);
        if (kh) { for (int r = 0; r < 4; ++r) part[r][wv][lane] = acm[r]; }
        __syncthreads();
        if (!kh) {
            for (int r = 0; r < 4; ++r) {
                int ch = (wv << 4) + colj[r];
                Pg[((long)b * SS + s0 + rowi[r]) * HH + ch]
                    = acm[r] + part[r][wv][lane] + (double)b1[ch];
            }
        }
    }
}

// ---------------------------------------------------------------------------
// Kernel 2: edge sign test, f32 fast path + exact f64 recompute for edges
// with |acc| < 3e-3 (f32 error bound ~5e-5; deterministic per input).
// ---------------------------------------------------------------------------
__global__ __launch_bounds__(256) void edges(
    const double* __restrict__ Qg, const double* __restrict__ Pg,
    const float* __restrict__ w2, const float* __restrict__ b2,
    const float* __restrict__ gum, float* __restrict__ out)
{
    const int b   = blockIdx.y;
    const int tit = blockIdx.x >> 3;
    const int tjt = blockIdx.x & 7;
    const int t   = threadIdx.x;
    const int ti  = t >> 4, tj = t & 15;
    const int i   = tit * 16 + ti;
    const int j   = tjt * 16 + tj;
    float* op = out + ((long)b * SS + i) * SS + j;

    if (tjt < tit) { *op = 0.0f; return; }

    __shared__ float Plf[16][68];
    __shared__ float Qlf[16][68];
    __shared__ float dwl[64];

    if (t < 64) dwl[t] = w2[t] - w2[64 + t];
    for (int idx = t; idx < 1024; idx += 256) {
        int r = idx >> 6, c = idx & 63;
        Plf[r][c] = (float)Pg[((long)b * SS + tit * 16 + r) * HH + c];
        Qlf[r][c] = (float)Qg[((long)b * SS + tjt * 16 + r) * HH + c];
    }
    __syncthreads();

    if (j <= i) { *op = 0.0f; return; }

    long e = (long)b * SS * SS + (long)i * SS + j;
    const float2 uv = *(const float2*)(gum + e * 2);
    float basef = (b2[0] - b2[1]) - logf(-logf(uv.x)) + logf(-logf(uv.y));

    const float2* Pr = (const float2*)(&Plf[ti][0]);
    const float2* Qr = (const float2*)(&Qlf[tj][0]);
    const float2* Dr = (const float2*)dwl;
    float s0 = 0.f, s1 = 0.f;
    #pragma unroll
    for (int k2 = 0; k2 < 32; ++k2) {
        float2 pv = Pr[k2], qv = Qr[k2], dv = Dr[k2];
        float v0 = pv.x + qv.x; v0 = v0 > 0.f ? v0 : 0.f;
        float v1 = pv.y + qv.y; v1 = v1 > 0.f ? v1 : 0.f;
        s0 += v0 * dv.x; s1 += v1 * dv.y;
    }
    float tot = basef + s0 + s1;

    if (fabsf(tot) < 3e-3f) {          // exact f64 recompute (rare)
        const double* Prd = Pg + ((long)b * SS + i) * HH;
        const double* Qrd = Qg + ((long)b * SS + j) * HH;
        double acc = (double)b2[0] - (double)b2[1]
                   - log(-log((double)uv.x)) + log(-log((double)uv.y));
        for (int k = 0; k < 64; ++k) {
            double v = Prd[k] + Qrd[k];
            if (v > 0.0) acc += v * ((double)w2[k] - (double)w2[64 + k]);
        }
        *op = (acc >= 0.0) ? 1.0f : 0.0f;
    } else {
        *op = (tot >= 0.f) ? 1.0f : 0.0f;
    }
}

extern "C" void kernel_launch(void* const* d_in, const int* in_sizes, int n_in,
                              void* d_out, int out_size, void* d_ws, size_t ws_size,
                              hipStream_t stream) {
    const float* data = (const float*)d_in[0];
    const float* w11  = (const float*)d_in[1];
    const float* b11  = (const float*)d_in[2];
    const float* w12  = (const float*)d_in[3];
    const float* b12  = (const float*)d_in[4];
    const float* w21  = (const float*)d_in[5];
    const float* b21  = (const float*)d_in[6];
    const float* w22  = (const float*)d_in[7];
    const float* b22  = (const float*)d_in[8];
    const float* w31  = (const float*)d_in[9];
    const float* b31  = (const float*)d_in[10];
    const float* wf   = (const float*)d_in[11];
    const float* bf   = (const float*)d_in[12];
    const float* w1   = (const float*)d_in[13];
    const float* b1   = (const float*)d_in[14];
    const float* w2   = (const float*)d_in[15];
    const float* b2   = (const float*)d_in[16];
    const float* gum  = (const float*)d_in[17];
    float* out = (float*)d_out;

    double* Qg = (double*)d_ws;                      // 2 MB
    double* Pg = Qg + (long)BB * SS * HH;            // 2 MB
    float*  Wt = (float*)(Pg + (long)BB * SS * HH);  // 63488 f32

    prep_weights<<<248, 256, 0, stream>>>(w11, w21, w12, w22, w31, wf, w1, Wt);
    fused_front<<<dim3(8, BB), 512, 0, stream>>>(
        data, b11, b12, b21, b22, b31, bf, b1, Wt, Qg, Pg);
    edges<<<dim3(64, BB), 256, 0, stream>>>(Qg, Pg, w2, b2, gum, out);
}